// Round 10
// baseline (128.168 us; speedup 1.0000x reference)
//
#include <hip/hip_runtime.h>
#include <math.h>

#define D_BINS 59
#define CO     64
#define CI     256
#define NB     4
#define NC     6
#define H_IMG  16
#define W_IMG  44
#define HW     704            // H_IMG * W_IMG
#define NPIX   (NB*NC*HW)     // 16896
#define XD     128
#define YD     128
#define ZD     7
#define NOUT   123            // D_BINS + CO

typedef float v2f __attribute__((ext_vector_type(2)));

// ---------------------------------------------------------------------------
// Double-precision rigid-transform inverse (matches np.linalg.inv to ~1e-15,
// avoiding depth-bin boundary flips downstream).
// ---------------------------------------------------------------------------
__device__ void inv_rigid(const float* __restrict__ M, float* __restrict__ o) {
    double a = M[0], b = M[1], c = M[2], t0 = M[3];
    double d = M[4], e = M[5], f = M[6], t1 = M[7];
    double g = M[8], h = M[9], ii = M[10], t2 = M[11];
    double A00 = e*ii - f*h, A01 = c*h - b*ii, A02 = b*f - c*e;
    double A10 = f*g - d*ii, A11 = a*ii - c*g, A12 = c*d - a*f;
    double A20 = d*h - e*g,  A21 = b*g - a*h,  A22 = a*e - b*d;
    double det = a*A00 + b*A10 + c*A20;
    double inv = 1.0 / det;
    double r00 = A00*inv, r01 = A01*inv, r02 = A02*inv;
    double r10 = A10*inv, r11 = A11*inv, r12 = A12*inv;
    double r20 = A20*inv, r21 = A21*inv, r22 = A22*inv;
    o[0] = (float)r00; o[1] = (float)r01; o[2]  = (float)r02;
    o[3] = (float)(-(r00*t0 + r01*t1 + r02*t2));
    o[4] = (float)r10; o[5] = (float)r11; o[6]  = (float)r12;
    o[7] = (float)(-(r10*t0 + r11*t1 + r12*t2));
    o[8] = (float)r20; o[9] = (float)r21; o[10] = (float)r22;
    o[11] = (float)(-(r20*t0 + r21*t1 + r22*t2));
}

// ---------------------------------------------------------------------------
// Kernel 1: prep (verbatim R9). W (123x256) -> wt2 k-pair-interleaved +
// transposed (o zero-padded to 128): wt2[(k/2)*256 + o*2 + (k&1)].
// Block 0 also inverts the 24 cam2ego matrices.
// ---------------------------------------------------------------------------
__global__ __launch_bounds__(256) void k_pre(
    const float* __restrict__ wd, const float* __restrict__ c2e,
    float* __restrict__ wt2, float* __restrict__ e2c) {
    const int o = blockIdx.x;   // 0..127
    const int k = threadIdx.x;  // 0..255
    float v = (o < NOUT) ? wd[(size_t)o * CI + k] : 0.f;
    wt2[(size_t)(k >> 1) * 256 + o * 2 + (k & 1)] = v;
    if (blockIdx.x == 0 && k < NB * NC)
        inv_rigid(c2e + k * 16, e2c + k * 12);
}

// ---------------------------------------------------------------------------
// Kernel 2: depth/feat head. Same shape as R9 (grid 264x2, 512 thr, wave wv
// owns o-strip o0 = 64*by + 8*wv, lane = px). ONE change: the k2 loop is
// split into 8 sub-chunks of 4 k2, and each sub-chunk's W block (8 o x 8 k
// = 16 float4) is BATCH-LOADED into named register locals before the
// compute. Every prior variant (R2/R5/R8/R9) dereferenced W from memory
// per-k2 behind the uniform pointer — one ~200-300 cyc memory round-trip
// per 16 VALU cycles that TLP never hid (5 structures, all ~40 us,
// VALUBusy ~14%). Batching gives 16 outstanding requests + one wait per
// 4 k2. Registers: acc 16 + wb 64 + misc ~= 100 < 128 cap -> no spill
// (R7's register-W failed at 128+16 needed vs 48 allocated).
// Per-output k-ascending fma order unchanged -> bit-identical numerics.
// ---------------------------------------------------------------------------
__global__ __launch_bounds__(512, 4) void k_head(
    const float* __restrict__ img, const float* __restrict__ wt2,
    const float* __restrict__ bd, float* __restrict__ depth_out,
    float* __restrict__ feat_ws) {
    __shared__ float smem[64 * 69 + 64];  // staging 32x130 overlaid, X[64][69] after
    float* S = smem + 64 * 69;

    const int tid = threadIdx.x;         // 0..511
    const int wv  = tid >> 6;            // 0..7
    const int ln  = tid & 63;            // px
    const int p0  = blockIdx.x * 64;     // 64 | 704 -> tile never crosses (b,n)
    const int bn  = p0 / HW;
    const int hw0 = p0 - bn * HW;
    const int ob  = blockIdx.y << 6;     // 0 or 64
    const int o0  = __builtin_amdgcn_readfirstlane(ob + (wv << 3));

    const float* imgb = img + (size_t)bn * CI * HW + hw0;

    v2f acc[8];                           // {even-k, odd-k} partial sums
#pragma unroll
    for (int j = 0; j < 8; ++j) acc[j] = (v2f)(0.f);

    for (int kc = 0; kc < 4; ++kc) {
        // stage A chunk: 64 k x 64 px, k-pair interleaved, row stride 130
        // (identical to R9: coalesced 256B global rows, 2-way free LDS writes)
#pragma unroll
        for (int it = 0; it < 8; ++it) {
            int i = tid + it * 512;
            int kl = i >> 6, px = i & 63;
            smem[(kl >> 1) * 130 + px * 2 + (kl & 1)] =
                imgb[(size_t)(kc * 64 + kl) * HW + px];
        }
        __syncthreads();
#pragma unroll 1
        for (int sc = 0; sc < 8; ++sc) {  // 8 sub-chunks x 4 k2
            // ---- batch-load W sub-chunk into registers (one burst) ----
            const float* wp = wt2 + (size_t)(kc * 32 + sc * 4) * 256 + o0 * 2;
            float4 wb[16];
#pragma unroll
            for (int q = 0; q < 4; ++q) {
                const float4* w4 = (const float4*)(wp + q * 256);
                wb[q * 4 + 0] = w4[0];
                wb[q * 4 + 1] = w4[1];
                wb[q * 4 + 2] = w4[2];
                wb[q * 4 + 3] = w4[3];
            }
            // ---- compute 4 k2 against registers ----
#pragma unroll
            for (int q = 0; q < 4; ++q) {
                int k2 = sc * 4 + q;
                v2f a = *(const v2f*)(smem + k2 * 130 + ln * 2);  // conflict-free b64
                const v2f* w = (const v2f*)(&wb[q * 4]);
#pragma unroll
                for (int j = 0; j < 8; ++j)
                    acc[j] = __builtin_elementwise_fma(a, w[j], acc[j]);
            }
        }
        __syncthreads();
    }

    // epilogue into X[64][69] (odd stride -> conflict-free column writes)
    float* X = smem;
#pragma unroll
    for (int j = 0; j < 8; ++j) {
        int o = o0 + j;
        if (o < NOUT)
            X[ln * 69 + (o - ob)] = (acc[j].x + acc[j].y) + bd[o];
    }
    __syncthreads();

    if (ob == 0) {
        // feat c = 0..4 from cols 59..63 (320 elems)
        if (tid < 320) {
            int p = tid / 5, c = tid - p * 5;
            feat_ws[(size_t)(p0 + p) * CO + c] = X[p * 69 + 59 + c];
        }
        // softmax over cols 0..58, one thread per pixel (same math as R5)
        if (tid < 64) {
            float* row = X + tid * 69;
            float m = row[0];
            for (int o = 1; o < D_BINS; ++o) m = fmaxf(m, row[o]);
            float s = 0.f;
            for (int o = 0; o < D_BINS; ++o) {
                float e = __expf(row[o] - m);
                row[o] = e;
                s += e;
            }
            S[tid] = 1.f / s;
        }
        __syncthreads();
        // depth: contiguous [p0*59, (p0+64)*59) -> coalesced
        for (int g = tid; g < 64 * D_BINS; g += 512) {
            int p = g / D_BINS;
            int o = g - p * D_BINS;
            depth_out[(size_t)p0 * D_BINS + g] = X[p * 69 + o] * S[p];
        }
    } else {
        // feat c = 5..63 from cols 0..58 (o = 64..122; o >= 123 dropped)
        for (int g = tid; g < 64 * D_BINS; g += 512) {
            int p = g / D_BINS;
            int j = g - p * D_BINS;
            feat_ws[(size_t)(p0 + p) * CO + 5 + j] = X[p * 69 + j];
        }
    }
}

// ---------------------------------------------------------------------------
// Kernel 3: project voxels, gather depth weight + feat, splat to BEV.
// Verbatim R9 (best measured): 1024 blocks (4/CU), precomputed e2c.
// Per camera n: projection phase computes each (x,z) sample's {hw, weight}
// once into LDS; accumulate phase broadcasts to the 4 channel-quarter
// threads (feat gathers + FMAs only).
// ---------------------------------------------------------------------------
__global__ __launch_bounds__(256) void k_splat(
    const float* __restrict__ e2c, const float* __restrict__ Kmat,
    const float* __restrict__ depth_g, const float* __restrict__ feat_ws,
    float* __restrict__ bev) {
    __shared__ int   hw_s[ZD][64];
    __shared__ float wgt_s[ZD][64];

    const int tx = threadIdx.x;          // 0..63 -> x
    const int cq = threadIdx.y;          // 0..3  -> channel quarter / z-slice
    const int x = blockIdx.x * 64 + tx;
    const int y = blockIdx.y;
    const int b = blockIdx.z;
    const float wx = (float)x * 0.8f + (-51.2f);
    const float wy = (float)y * 0.8f + (-51.2f);

    float acc[16];
#pragma unroll
    for (int m = 0; m < 16; ++m) acc[m] = 0.f;

    for (int n = 0; n < NC; ++n) {
        const int bn = b * NC + n;
        const float* E = e2c + bn * 12;
        const float* Km = Kmat + bn * 9;
        const float k00 = Km[0], k01 = Km[1], k02 = Km[2];
        const float k10 = Km[3], k11 = Km[4], k12 = Km[5];
        const float e02 = E[2], e12 = E[6], e22 = E[10];
        const float bx0 = E[0] * wx + E[1] * wy + E[3];
        const float bx1 = E[4] * wx + E[5] * wy + E[7];
        const float bx2 = E[8] * wx + E[9] * wy + E[11];

        // ---- projection phase: thread (tx,cq) owns z = cq and cq+4 ----
#pragma unroll
        for (int zz = 0; zz < 2; ++zz) {
            const int z = cq + zz * 4;
            if (z < ZD) {
                const float wz = -2.5f + (float)z;
                const float cx = bx0 + e02 * wz;
                const float cy = bx1 + e12 * wz;
                const float cz = bx2 + e22 * wz;
                const float zs = fmaxf(cz, 0.1f);
                const float rz = 1.0f / zs;         // IEEE divide
                const float xn = cx * rz;
                const float yn = cy * rz;
                const float fu = (k00 * xn + k01 * yn + k02) * 0.0625f;
                const float fv = (k10 * xn + k11 * yn + k12) * 0.0625f;
                const int bin = (int)(cz - 1.0f);   // trunc, matches astype(int32)
                const bool valid = (fu >= 0.f) & (fu < (float)W_IMG) &
                                   (fv >= 0.f) & (fv < (float)H_IMG) &
                                   (cz > 0.5f) & (bin >= 0) & (bin < D_BINS);
                int hw = -1;
                float wgt = 0.f;
                if (valid) {
                    int u = (int)fu;                // valid => in range
                    int v = (int)fv;
                    hw = v * W_IMG + u;
                    wgt = depth_g[((size_t)bn * HW + hw) * D_BINS + bin];
                }
                hw_s[z][tx] = hw;
                wgt_s[z][tx] = wgt;
            }
        }
        __syncthreads();

        // ---- accumulate phase: z ascending ----
#pragma unroll
        for (int z = 0; z < ZD; ++z) {
            const int hw = hw_s[z][tx];       // same addr across cq: broadcast
            if (hw >= 0) {
                const float wgt = wgt_s[z][tx];
                const float4* fp =
                    (const float4*)(feat_ws + ((size_t)bn * HW + hw) * CO + cq * 16);
                float4 f0 = fp[0], f1 = fp[1], f2 = fp[2], f3 = fp[3];
                acc[0]  = fmaf(wgt, f0.x, acc[0]);
                acc[1]  = fmaf(wgt, f0.y, acc[1]);
                acc[2]  = fmaf(wgt, f0.z, acc[2]);
                acc[3]  = fmaf(wgt, f0.w, acc[3]);
                acc[4]  = fmaf(wgt, f1.x, acc[4]);
                acc[5]  = fmaf(wgt, f1.y, acc[5]);
                acc[6]  = fmaf(wgt, f1.z, acc[6]);
                acc[7]  = fmaf(wgt, f1.w, acc[7]);
                acc[8]  = fmaf(wgt, f2.x, acc[8]);
                acc[9]  = fmaf(wgt, f2.y, acc[9]);
                acc[10] = fmaf(wgt, f2.z, acc[10]);
                acc[11] = fmaf(wgt, f2.w, acc[11]);
                acc[12] = fmaf(wgt, f3.x, acc[12]);
                acc[13] = fmaf(wgt, f3.y, acc[13]);
                acc[14] = fmaf(wgt, f3.z, acc[14]);
                acc[15] = fmaf(wgt, f3.w, acc[15]);
            }
        }
        __syncthreads();   // LDS reused next n
    }
    // out[b][c][y][x], c = cq*16 + m; 64 lanes = consecutive x -> coalesced
    float* ob = bev + (((size_t)b * CO + cq * 16) * YD + y) * XD + x;
#pragma unroll
    for (int m = 0; m < 16; ++m) ob[(size_t)m * YD * XD] = acc[m];
}

extern "C" void kernel_launch(void* const* d_in, const int* in_sizes, int n_in,
                              void* d_out, int out_size, void* d_ws, size_t ws_size,
                              hipStream_t stream) {
    const float* img  = (const float*)d_in[0];  // (B,N,256,16,44)
    const float* c2e  = (const float*)d_in[1];  // (B,N,4,4)
    const float* Kmat = (const float*)d_in[2];  // (B,N,3,3)
    const float* wd   = (const float*)d_in[3];  // (123,256)
    const float* bd   = (const float*)d_in[4];  // (123,)
    float* bev = (float*)d_out;                         // (B,64,128,128)
    float* depth_out = bev + (size_t)NB * CO * YD * XD; // (B,N,16,44,59)
    float* feat_ws = (float*)d_ws;                      // NPIX*64 floats
    float* wt2 = feat_ws + (size_t)NPIX * CO;           // 128*256 floats
    float* e2c = wt2 + 128 * 256;                       // 24*12 floats

    k_pre<<<128, 256, 0, stream>>>(wd, c2e, wt2, e2c);
    k_head<<<dim3(NPIX / 64, 2), 512, 0, stream>>>(img, wt2, bd, depth_out, feat_ws);
    k_splat<<<dim3(2, YD, NB), dim3(64, 4, 1), 0, stream>>>(e2c, Kmat, depth_out,
                                                            feat_ws, bev);
}